// Round 11
// baseline (190.693 us; speedup 1.0000x reference)
//
#include <hip/hip_runtime.h>

typedef int i32x4 __attribute__((ext_vector_type(4)));

#define QMAXF 127.0f
#define LGKM0() asm volatile("s_waitcnt lgkmcnt(0)" ::: "memory")
#define BAR()   __builtin_amdgcn_s_barrier()

// ---------------------------------------------------------------------------
// Weight quantization: one block per output row (cout). ~2 us. Proven R3-R8.
// ---------------------------------------------------------------------------
__global__ __launch_bounds__(256) void quant_w_kernel(
    const float* __restrict__ w, const float* __restrict__ act_scale,
    signed char* __restrict__ qw, float* __restrict__ wscale)
{
    const int row = blockIdx.x;
    const int t   = threadIdx.x;
    const float s = act_scale[0];

    float4 v = *reinterpret_cast<const float4*>(w + (size_t)row * 1024 + t * 4);
    float a0 = v.x * s, a1 = v.y * s, a2 = v.z * s, a3 = v.w * s;
    float m = fmaxf(fmaxf(fabsf(a0), fabsf(a1)), fmaxf(fabsf(a2), fabsf(a3)));

    #pragma unroll
    for (int i = 1; i < 64; i <<= 1)
        m = fmaxf(m, __shfl_xor(m, i));

    __shared__ float wmax[4];
    if ((t & 63) == 0) wmax[t >> 6] = m;
    __syncthreads();
    m = fmaxf(fmaxf(wmax[0], wmax[1]), fmaxf(wmax[2], wmax[3]));

    const float wsc = m / QMAXF;

    int q0 = (int)rintf(a0 / wsc);
    int q1 = (int)rintf(a1 / wsc);
    int q2 = (int)rintf(a2 / wsc);
    int q3 = (int)rintf(a3 / wsc);
    int packed = (q0 & 255) | ((q1 & 255) << 8) | ((q2 & 255) << 16) | ((q3 & 255) << 24);
    reinterpret_cast<int*>(qw)[row * 256 + t] = packed;

    if (t == 0) wscale[row] = wsc;
}

// ---------------------------------------------------------------------------
// Fused quant(x)+GEMM, register-budget-fixed (4th fusion attempt):
//  tile 256(M)x128(N), BK=128 int8; 8 waves 4Mx2N -> per-wave 64x64,
//  acc[4][4]=64 regs (unified budget ~210 < 256 cap at 2 waves/SIMD —
//  R7's spill was 280). LDS: A dbuf 2x32KB + B dbuf 2x16KB = 96 KB.
//  A-path: x f32 -> regs (16 dwordx4, issued 1 tile ahead) -> in-register
//  quant (rintf/clip, ops identical to passing R5-R8) -> swizzled ds_write.
//  B-path: global_load_lds, pre-swizzled source slot^(row&7), linear dest.
//  Counted waits: quant's implicit vmcnt retires exactly the x loads
//  (issue order keeps B stages newer); explicit vmcnt(16) at P2 retires
//  B(T+1) and leaves x(T+2)'s 16 loads in flight. Never vmcnt(0) mid-loop.
//  One barrier/phase: all LDS writes target buf (T+1)&1 whose last reader
//  was tile T-1 phase P1 — >=2 barriers upstream. XCD swizzle n-minor:
//  8 consecutive same-XCD blocks share each 1MB x panel (L2 reuse).
// ---------------------------------------------------------------------------
#define NT 8   // K / 128

__global__ __launch_bounds__(512, 2) void gemm_fused_kernel(
    const float* __restrict__ x, const signed char* __restrict__ qw,
    const float* __restrict__ act_scale, const float* __restrict__ wscale,
    const float* __restrict__ bias, float* __restrict__ out, int M)
{
    const int K = 1024, N = 1024;
    __shared__ __align__(16) signed char As[2][256 * 128];  // 64 KB
    __shared__ __align__(16) signed char Bs[2][128 * 128];  // 32 KB

    const int t    = threadIdx.x;
    const int lane = t & 63;
    const int w    = t >> 6;      // wave 0..7
    const int wr   = w >> 1;      // 0..3 (M 64-row group)
    const int wc   = w & 1;       // 0..1 (N 64-col group)
    const int lrow = lane & 15;
    const int ks   = lane >> 4;   // 16B K-slot 0..3

    // XCD-aware bijective swizzle; nwg = (M/256)*(N/128) = 1024, %8==0.
    const int nwg = gridDim.x;
    const int cpx = nwg >> 3;
    const int bid = blockIdx.x;
    const int swz = (bid & 7) * cpx + (bid >> 3);
    const int m0 = (swz >> 3) * 256;   // n-minor: 8 consecutive blocks share x panel
    const int n0 = (swz & 7) * 128;

    const float rinv = 1.0f / act_scale[0];

    i32x4 acc[4][4] = {};   // 64 regs
    i32x4 Ar[4][2];         // 32
    i32x4 Br[2][2];         // 16 (nf-pair per phase)
    float4 XA[8], XB[8];    // 64: x f32 for one tile (halves h0/h1)

    // x rows handled by this thread: h*128 + (t>>2); 32 consecutive f32.
    auto XLD = [&](int T, int h, float4 (&X)[8]) {
        const float* p = x + (size_t)(m0 + h * 128 + (t >> 2)) * K + T * 128 + (t & 3) * 32;
        #pragma unroll
        for (int j = 0; j < 8; ++j) X[j] = *reinterpret_cast<const float4*>(p + j * 4);
    };
    // quantize 32 f32 -> 32 int8, swizzled ds_write (2 x b128)
    auto AQW = [&](int h, int buf, const float4 (&X)[8]) {
        int pk[8];
        #pragma unroll
        for (int c = 0; c < 8; ++c) {
            int q0 = (int)rintf(fminf(fmaxf(X[c].x * rinv, -QMAXF), QMAXF));
            int q1 = (int)rintf(fminf(fmaxf(X[c].y * rinv, -QMAXF), QMAXF));
            int q2 = (int)rintf(fminf(fmaxf(X[c].z * rinv, -QMAXF), QMAXF));
            int q3 = (int)rintf(fminf(fmaxf(X[c].w * rinv, -QMAXF), QMAXF));
            pk[c] = (q0 & 255) | ((q1 & 255) << 8) | ((q2 & 255) << 16) | ((q3 & 255) << 24);
        }
        const int row = h * 128 + (t >> 2);
        signed char* base = &As[buf][0] + row * 128;
        const int s0 = (2 * (t & 3)) ^ (row & 7);
        const int s1 = (2 * (t & 3) + 1) ^ (row & 7);
        *reinterpret_cast<i32x4*>(base + s0 * 16) = i32x4{pk[0], pk[1], pk[2], pk[3]};
        *reinterpret_cast<i32x4*>(base + s1 * 16) = i32x4{pk[4], pk[5], pk[6], pk[7]};
    };
    // stage one 8KB B half: 1 x gload_lds(16B)/thread, pre-swizzled source
    auto BST = [&](int T, int h) {
        const int row = h * 64 + (t >> 3);
        const int sl  = t & 7;
        const int gs  = sl ^ (row & 7);
        const signed char* src = qw + (size_t)(n0 + row) * K + T * 128 + gs * 16;
        __builtin_amdgcn_global_load_lds(
            (const __attribute__((address_space(1))) void*)src,
            (__attribute__((address_space(3))) void*)(&Bs[T & 1][0] + (h * 512 + t) * 16),
            16, 0, 0);
    };
    auto LDA = [&](int buf) {
        #pragma unroll
        for (int mf = 0; mf < 4; ++mf) {
            const int row = wr * 64 + mf * 16 + lrow;
            #pragma unroll
            for (int kk = 0; kk < 2; ++kk) {
                const int slot = (kk * 4 + ks) ^ (row & 7);
                Ar[mf][kk] = *reinterpret_cast<const i32x4*>(&As[buf][0] + row * 128 + slot * 16);
            }
        }
    };
    auto LDB = [&](int buf, int nh) {
        #pragma unroll
        for (int nf = 0; nf < 2; ++nf) {
            const int row = wc * 64 + (nh * 2 + nf) * 16 + lrow;
            #pragma unroll
            for (int kk = 0; kk < 2; ++kk) {
                const int slot = (kk * 4 + ks) ^ (row & 7);
                Br[nf][kk] = *reinterpret_cast<const i32x4*>(&Bs[buf][0] + row * 128 + slot * 16);
            }
        }
    };
    auto MM = [&](int nh) {
        __builtin_amdgcn_s_setprio(1);
        #pragma unroll
        for (int mf = 0; mf < 4; ++mf)
            #pragma unroll
            for (int nf = 0; nf < 2; ++nf)
                #pragma unroll
                for (int kk = 0; kk < 2; ++kk)
                    acc[mf][nh * 2 + nf] = __builtin_amdgcn_mfma_i32_16x16x64_i8(
                        Ar[mf][kk], Br[nf][kk], acc[mf][nh * 2 + nf], 0, 0, 0);
        __builtin_amdgcn_s_setprio(0);
    };

    // ---- prologue: B(0); x(0)->A(0) (quant wait also retires B(0)); x(1) ----
    BST(0, 0); BST(0, 1);
    XLD(0, 0, XA); XLD(0, 1, XB);
    AQW(0, 0, XA); AQW(1, 0, XB);
    XLD(1, 0, XA); XLD(1, 1, XB);       // x(1): 16 loads in flight
    LGKM0(); BAR();

    #pragma unroll
    for (int T = 0; T < NT; ++T) {
        const int buf = T & 1, nxt = buf ^ 1;
        // ---- P1: frags; quant A(T+1)h0 (waits x(T+1)h0, the 8 oldest);
        //          stage B(T+1)h0; 16 MFMA (nh0) ----
        LDA(buf); LDB(buf, 0);
        if (T + 1 < NT) { AQW(0, nxt, XA); BST(T + 1, 0); }
        MM(0);
        LGKM0(); BAR();
        // ---- P2: frags; quant h1; stage B(T+1)h1; issue x(T+2);
        //          vmcnt(16): retire B(T+1), keep x(T+2) in flight ----
        LDB(buf, 1);
        if (T + 1 < NT) { AQW(1, nxt, XB); BST(T + 1, 1); }
        if (T + 2 < NT) { XLD(T + 2, 0, XA); XLD(T + 2, 1, XB); }
        if (T + 2 < NT)      { asm volatile("s_waitcnt vmcnt(16)" ::: "memory"); }
        else if (T + 1 < NT) { asm volatile("s_waitcnt vmcnt(0)"  ::: "memory"); }
        MM(1);
        LGKM0(); BAR();
    }

    // ---- epilogue: dequant + bias ----
    float wsv[4], bv[4];
    int   gnc[4];
    #pragma unroll
    for (int nf = 0; nf < 4; ++nf) {
        const int gn = n0 + wc * 64 + nf * 16 + lrow;
        gnc[nf] = gn;
        wsv[nf] = wscale[gn];
        bv[nf]  = bias[gn];
    }
    #pragma unroll
    for (int mf = 0; mf < 4; ++mf) {
        #pragma unroll
        for (int rr = 0; rr < 4; ++rr) {
            const int gm = m0 + wr * 64 + mf * 16 + ks * 4 + rr;
            float* orow = out + (size_t)gm * N;
            #pragma unroll
            for (int nf = 0; nf < 4; ++nf)
                orow[gnc[nf]] = (float)acc[mf][nf][rr] * wsv[nf] + bv[nf];
        }
    }
}

// ---------------------------------------------------------------------------
extern "C" void kernel_launch(void* const* d_in, const int* in_sizes, int n_in,
                              void* d_out, int out_size, void* d_ws, size_t ws_size,
                              hipStream_t stream)
{
    const float* x         = (const float*)d_in[0];
    const float* weight    = (const float*)d_in[1];
    const float* bias      = (const float*)d_in[2];
    const float* act_scale = (const float*)d_in[3];
    float* out             = (float*)d_out;

    const int K = 1024;
    const int N = 1024;
    const int M = in_sizes[0] / K;   // 32768

    // workspace: qw (N*K int8) | wscale (N f32)
    char* wsb = (char*)d_ws;
    signed char* qw  = (signed char*)wsb;
    float*       wsc = (float*)(wsb + (size_t)N * K);

    quant_w_kernel<<<N, 256, 0, stream>>>(weight, act_scale, qw, wsc);

    const int grid = (M / 256) * (N / 128);   // 1024, divisible by 8
    gemm_fused_kernel<<<grid, 512, 0, stream>>>(x, qw, act_scale, wsc, bias, out, M);
}

// Round 13
// 94.754 us; speedup vs baseline: 2.0125x; 2.0125x over previous
//
#include <hip/hip_runtime.h>

typedef int   i32x4 __attribute__((ext_vector_type(4)));
typedef float f32x4 __attribute__((ext_vector_type(4)));

#define QMAXF 127.0f
#define BAR()   __builtin_amdgcn_s_barrier()
#define LGKM0() asm volatile("s_waitcnt lgkmcnt(0)" ::: "memory")

// ---------------------------------------------------------------------------
// Weight quantization: one block per output row (cout). ~2 us. Proven R3-R11.
// ---------------------------------------------------------------------------
__global__ __launch_bounds__(256) void quant_w_kernel(
    const float* __restrict__ w, const float* __restrict__ act_scale,
    signed char* __restrict__ qw, float* __restrict__ wscale)
{
    const int row = blockIdx.x;
    const int t   = threadIdx.x;
    const float s = act_scale[0];

    float4 v = *reinterpret_cast<const float4*>(w + (size_t)row * 1024 + t * 4);
    float a0 = v.x * s, a1 = v.y * s, a2 = v.z * s, a3 = v.w * s;
    float m = fmaxf(fmaxf(fabsf(a0), fabsf(a1)), fmaxf(fabsf(a2), fabsf(a3)));

    #pragma unroll
    for (int i = 1; i < 64; i <<= 1)
        m = fmaxf(m, __shfl_xor(m, i));

    __shared__ float wmax[4];
    if ((t & 63) == 0) wmax[t >> 6] = m;
    __syncthreads();
    m = fmaxf(fmaxf(wmax[0], wmax[1]), fmaxf(wmax[2], wmax[3]));

    const float wsc = m / QMAXF;

    int q0 = (int)rintf(a0 / wsc);
    int q1 = (int)rintf(a1 / wsc);
    int q2 = (int)rintf(a2 / wsc);
    int q3 = (int)rintf(a3 / wsc);
    int packed = (q0 & 255) | ((q1 & 255) << 8) | ((q2 & 255) << 16) | ((q3 & 255) << 24);
    reinterpret_cast<int*>(qw)[row * 256 + t] = packed;

    if (t == 0) wscale[row] = wsc;
}

// ---------------------------------------------------------------------------
// Activation quantization (BW floor ~24 us). Nontemporal x reads via native
// ext_vector f32x4 (HIP float4 struct is rejected by the builtin): x is dead
// after this pass — keep it out of L2 so xq/qw panels stay resident for gemm.
// ---------------------------------------------------------------------------
__global__ __launch_bounds__(256) void quant_x_kernel(
    const float* __restrict__ x, const float* __restrict__ act_scale,
    signed char* __restrict__ xq)
{
    const float s = act_scale[0];
    const size_t i = ((size_t)blockIdx.x * 256 + threadIdx.x) * 4;
    f32x4 v = __builtin_nontemporal_load(reinterpret_cast<const f32x4*>(x + i));
    int q0 = (int)rintf(fminf(fmaxf(v.x / s, -QMAXF), QMAXF));
    int q1 = (int)rintf(fminf(fmaxf(v.y / s, -QMAXF), QMAXF));
    int q2 = (int)rintf(fminf(fmaxf(v.z / s, -QMAXF), QMAXF));
    int q3 = (int)rintf(fminf(fmaxf(v.w / s, -QMAXF), QMAXF));
    int packed = (q0 & 255) | ((q1 & 255) << 8) | ((q2 & 255) << 16) | ((q3 & 255) << 24);
    reinterpret_cast<int*>(xq)[i >> 2] = packed;
}

// ---------------------------------------------------------------------------
// int8 GEMM — byte-identical to the best-measured R4 kernel (256x256 tile,
// 8 waves, BK=128, 8-phase counted-vmcnt schedule, slot^(row&7) swizzle via
// pre-swizzled global source, XCD-aware bijective swizzle) EXCEPT the
// epilogue C-stores are nontemporal (write-once stream, bypass L2).
// ---------------------------------------------------------------------------
#define BM 256
#define BN 256
#define BKB 128
#define NTILES 8   // K / BKB

__global__ __launch_bounds__(512, 2) void gemm_i8_kernel(
    const signed char* __restrict__ xq, const signed char* __restrict__ qw,
    const float* __restrict__ wscale, const float* __restrict__ bias,
    float* __restrict__ out, int M)
{
    const int K = 1024, N = 1024;
    __shared__ __align__(16) signed char lds[2 * 2 * 2 * 16384]; // 128 KiB

    const int t    = threadIdx.x;
    const int lane = t & 63;
    const int w    = t >> 6;
    const int wr   = w >> 2;
    const int wc   = w & 3;
    const int lrow = lane & 15;
    const int ks   = lane >> 4;
    const int r8   = lane >> 3;
    const int sl   = lane & 7;

    const int nwg = gridDim.x;
    const int cpx = nwg >> 3;
    const int bid = blockIdx.x;
    const int swz = (bid & 7) * cpx + (bid >> 3);
    const int m0 = (swz >> 2) * BM;
    const int n0 = (swz & 3) * BN;

    i32x4 acc[8][4] = {};
    i32x4 Ar[4][2];
    i32x4 Br[2][2][2];

    auto STAGE = [&](int kt, int ab, int h) {
        const signed char* g = ab ? qw : xq;
        const int grow0 = (ab ? n0 : m0) + h * 128;
        signed char* lb = lds + (((kt & 1) * 2 + ab) * 2 + h) * 16384;
        #pragma unroll
        for (int j = 0; j < 2; ++j) {
            const int row = (j * 8 + w) * 8 + r8;
            const signed char* src =
                g + (size_t)(grow0 + row) * K + kt * BKB + ((sl ^ r8) << 4);
            __builtin_amdgcn_global_load_lds(
                (const __attribute__((address_space(1))) void*)src,
                (__attribute__((address_space(3))) void*)(lb + ((j * 8 + w) * 64 + lane) * 16),
                16, 0, 0);
        }
    };

    auto LDA = [&](int buf, int mh, i32x4 A[4][2]) {
        const signed char* base = lds + ((buf * 2 + 0) * 2 + wr) * 16384;
        #pragma unroll
        for (int mf = 0; mf < 4; ++mf) {
            const int row = mh * 64 + mf * 16 + lrow;
            #pragma unroll
            for (int kk = 0; kk < 2; ++kk) {
                const int slot = (kk * 4 + ks) ^ (lrow & 7);
                A[mf][kk] = *reinterpret_cast<const i32x4*>(base + row * 128 + slot * 16);
            }
        }
    };
    auto LDB = [&](int buf, int nh, i32x4 B[2][2]) {
        const signed char* base = lds + ((buf * 2 + 1) * 2 + (wc >> 1)) * 16384;
        #pragma unroll
        for (int nf = 0; nf < 2; ++nf) {
            const int row = (wc & 1) * 64 + nh * 32 + nf * 16 + lrow;
            #pragma unroll
            for (int kk = 0; kk < 2; ++kk) {
                const int slot = (kk * 4 + ks) ^ (lrow & 7);
                B[nf][kk] = *reinterpret_cast<const i32x4*>(base + row * 128 + slot * 16);
            }
        }
    };
    auto MM = [&](int mh, int nh, i32x4 A[4][2], i32x4 B[2][2]) {
        __builtin_amdgcn_s_setprio(1);
        #pragma unroll
        for (int mf = 0; mf < 4; ++mf)
            #pragma unroll
            for (int nf = 0; nf < 2; ++nf)
                #pragma unroll
                for (int kk = 0; kk < 2; ++kk)
                    acc[mh * 4 + mf][nh * 2 + nf] = __builtin_amdgcn_mfma_i32_16x16x64_i8(
                        A[mf][kk], B[nf][kk], acc[mh * 4 + mf][nh * 2 + nf], 0, 0, 0);
        __builtin_amdgcn_s_setprio(0);
    };

    // ---- prologue ----
    STAGE(0, 1, 0); STAGE(0, 1, 1); STAGE(0, 0, 0); STAGE(0, 0, 1);
    STAGE(1, 1, 0); STAGE(1, 1, 1);
    asm volatile("s_waitcnt vmcnt(4)" ::: "memory");
    BAR();

    #pragma unroll
    for (int it = 0; it < NTILES / 2; ++it) {
        const int T = 2 * it;
        // P1
        LDA(0, 0, Ar); LDB(0, 0, Br[0]);
        STAGE(T + 1, 0, 0);
        BAR(); LGKM0();
        MM(0, 0, Ar, Br[0]);
        BAR();
        // P2
        LDB(0, 1, Br[1]);
        STAGE(T + 1, 0, 1);
        BAR(); LGKM0();
        MM(0, 1, Ar, Br[1]);
        BAR();
        // P3
        LDA(0, 1, Ar);
        if (T + 2 < NTILES) STAGE(T + 2, 1, 0);
        BAR(); LGKM0();
        MM(1, 0, Ar, Br[0]);
        BAR();
        // P4
        if (T + 2 < NTILES) STAGE(T + 2, 1, 1);
        MM(1, 1, Ar, Br[1]);
        if (T + 2 < NTILES) { asm volatile("s_waitcnt vmcnt(4)" ::: "memory"); }
        else                { asm volatile("s_waitcnt vmcnt(0)" ::: "memory"); }
        BAR();
        // P5
        LDA(1, 0, Ar); LDB(1, 0, Br[0]);
        if (T + 2 < NTILES) STAGE(T + 2, 0, 0);
        BAR(); LGKM0();
        MM(0, 0, Ar, Br[0]);
        BAR();
        // P6
        LDB(1, 1, Br[1]);
        if (T + 2 < NTILES) STAGE(T + 2, 0, 1);
        BAR(); LGKM0();
        MM(0, 1, Ar, Br[1]);
        BAR();
        // P7
        LDA(1, 1, Ar);
        if (T + 3 < NTILES) STAGE(T + 3, 1, 0);
        BAR(); LGKM0();
        MM(1, 0, Ar, Br[0]);
        BAR();
        // P8
        if (T + 3 < NTILES) STAGE(T + 3, 1, 1);
        MM(1, 1, Ar, Br[1]);
        if (T + 3 < NTILES) { asm volatile("s_waitcnt vmcnt(4)" ::: "memory"); }
        BAR();
    }

    // ---- epilogue: dequant + bias; nontemporal C-stores (write-once) ----
    float wsv[4], bv[4];
    int   gnc[4];
    #pragma unroll
    for (int nf = 0; nf < 4; ++nf) {
        const int gn = n0 + wc * 64 + nf * 16 + lrow;
        gnc[nf] = gn;
        wsv[nf] = wscale[gn];
        bv[nf]  = bias[gn];
    }
    #pragma unroll
    for (int mf = 0; mf < 8; ++mf) {
        #pragma unroll
        for (int r = 0; r < 4; ++r) {
            const int gm = m0 + wr * 128 + mf * 16 + ks * 4 + r;
            float* orow = out + (size_t)gm * N;
            #pragma unroll
            for (int nf = 0; nf < 4; ++nf)
                __builtin_nontemporal_store(
                    (float)acc[mf][nf][r] * wsv[nf] + bv[nf], &orow[gnc[nf]]);
        }
    }
}

// ---------------------------------------------------------------------------
extern "C" void kernel_launch(void* const* d_in, const int* in_sizes, int n_in,
                              void* d_out, int out_size, void* d_ws, size_t ws_size,
                              hipStream_t stream)
{
    const float* x         = (const float*)d_in[0];
    const float* weight    = (const float*)d_in[1];
    const float* bias      = (const float*)d_in[2];
    const float* act_scale = (const float*)d_in[3];
    float* out             = (float*)d_out;

    const int K = 1024;
    const int N = 1024;
    const int M = in_sizes[0] / K;   // 32768

    // workspace: qw (N*K int8) | wscale (N f32, padded) | xq (M*K int8)
    char* wsb = (char*)d_ws;
    signed char* qw  = (signed char*)wsb;
    float*       wsc = (float*)(wsb + (size_t)N * K);
    signed char* xq  = (signed char*)(wsb + (size_t)N * K + 4096);

    quant_w_kernel<<<N, 256, 0, stream>>>(weight, act_scale, qw, wsc);
    quant_x_kernel<<<(int)(((size_t)M * K) / 1024), 256, 0, stream>>>(x, act_scale, xq);

    const int grid = (M / BM) * (N / BN);   // 512, divisible by 8
    gemm_i8_kernel<<<grid, 512, 0, stream>>>(xq, qw, wsc, bias, out, M);
}

// Round 17
// 81.537 us; speedup vs baseline: 2.3387x; 1.1621x over previous
//
#include <hip/hip_runtime.h>

typedef int   i32x4 __attribute__((ext_vector_type(4)));
typedef float f32x4 __attribute__((ext_vector_type(4)));

#define QMAXF 127.0f
#define BAR()   __builtin_amdgcn_s_barrier()
#define LGKM0() asm volatile("s_waitcnt lgkmcnt(0)" ::: "memory")

// ---------------------------------------------------------------------------
// Weight quantization: one block per output row (cout). ~2 us. Proven R3-R13.
// ---------------------------------------------------------------------------
__global__ __launch_bounds__(256) void quant_w_kernel(
    const float* __restrict__ w, const float* __restrict__ act_scale,
    signed char* __restrict__ qw, float* __restrict__ wscale)
{
    const int row = blockIdx.x;
    const int t   = threadIdx.x;
    const float s = act_scale[0];

    float4 v = *reinterpret_cast<const float4*>(w + (size_t)row * 1024 + t * 4);
    float a0 = v.x * s, a1 = v.y * s, a2 = v.z * s, a3 = v.w * s;
    float m = fmaxf(fmaxf(fabsf(a0), fabsf(a1)), fmaxf(fabsf(a2), fabsf(a3)));

    #pragma unroll
    for (int i = 1; i < 64; i <<= 1)
        m = fmaxf(m, __shfl_xor(m, i));

    __shared__ float wmax[4];
    if ((t & 63) == 0) wmax[t >> 6] = m;
    __syncthreads();
    m = fmaxf(fmaxf(wmax[0], wmax[1]), fmaxf(wmax[2], wmax[3]));

    const float wsc = m / QMAXF;

    int q0 = (int)rintf(a0 / wsc);
    int q1 = (int)rintf(a1 / wsc);
    int q2 = (int)rintf(a2 / wsc);
    int q3 = (int)rintf(a3 / wsc);
    int packed = (q0 & 255) | ((q1 & 255) << 8) | ((q2 & 255) << 16) | ((q3 & 255) << 24);
    reinterpret_cast<int*>(qw)[row * 256 + t] = packed;

    if (t == 0) wscale[row] = wsc;
}

// ---------------------------------------------------------------------------
// Activation quantization (BW floor ~24 us). Nontemporal x read (f32x4 native
// vector type): x is dead after this pass; measured R13 FETCH=21MB confirms
// xq/qw stay cache-resident for the gemm.
// ---------------------------------------------------------------------------
__global__ __launch_bounds__(256) void quant_x_kernel(
    const float* __restrict__ x, const float* __restrict__ act_scale,
    signed char* __restrict__ xq)
{
    const float s = act_scale[0];
    const size_t i = ((size_t)blockIdx.x * 256 + threadIdx.x) * 4;
    f32x4 v = __builtin_nontemporal_load(reinterpret_cast<const f32x4*>(x + i));
    int q0 = (int)rintf(fminf(fmaxf(v.x / s, -QMAXF), QMAXF));
    int q1 = (int)rintf(fminf(fmaxf(v.y / s, -QMAXF), QMAXF));
    int q2 = (int)rintf(fminf(fmaxf(v.z / s, -QMAXF), QMAXF));
    int q3 = (int)rintf(fminf(fmaxf(v.w / s, -QMAXF), QMAXF));
    int packed = (q0 & 255) | ((q1 & 255) << 8) | ((q2 & 255) << 16) | ((q3 & 255) << 24);
    reinterpret_cast<int*>(xq)[i >> 2] = packed;
}

// ---------------------------------------------------------------------------
// int8 GEMM — R4's best-measured kernel (256x256 tile, 8 waves, BK=128,
// 8-phase counted-vmcnt schedule, slot^(row&7) swizzle via pre-swizzled
// global source, XCD-aware bijective swizzle), normal C-stores (R13 proved
// nt stores cost +20us/+44MB), wscale/bias hoisted before the K-loop.
// ---------------------------------------------------------------------------
#define BM 256
#define BN 256
#define BKB 128
#define NTILES 8   // K / BKB

__global__ __launch_bounds__(512, 2) void gemm_i8_kernel(
    const signed char* __restrict__ xq, const signed char* __restrict__ qw,
    const float* __restrict__ wscale, const float* __restrict__ bias,
    float* __restrict__ out, int M)
{
    const int K = 1024, N = 1024;
    __shared__ __align__(16) signed char lds[2 * 2 * 2 * 16384]; // 128 KiB

    const int t    = threadIdx.x;
    const int lane = t & 63;
    const int w    = t >> 6;
    const int wr   = w >> 2;
    const int wc   = w & 3;
    const int lrow = lane & 15;
    const int ks   = lane >> 4;
    const int r8   = lane >> 3;
    const int sl   = lane & 7;

    const int nwg = gridDim.x;
    const int cpx = nwg >> 3;
    const int bid = blockIdx.x;
    const int swz = (bid & 7) * cpx + (bid >> 3);
    const int m0 = (swz >> 2) * BM;
    const int n0 = (swz & 3) * BN;

    // epilogue constants hoisted: no dependent-load chain in the block tail
    float wsv[4], bv[4];
    int   gnc[4];
    #pragma unroll
    for (int nf = 0; nf < 4; ++nf) {
        const int gn = n0 + wc * 64 + nf * 16 + lrow;
        gnc[nf] = gn;
        wsv[nf] = wscale[gn];
        bv[nf]  = bias[gn];
    }

    i32x4 acc[8][4] = {};
    i32x4 Ar[4][2];
    i32x4 Br[2][2][2];

    auto STAGE = [&](int kt, int ab, int h) {
        const signed char* g = ab ? qw : xq;
        const int grow0 = (ab ? n0 : m0) + h * 128;
        signed char* lb = lds + (((kt & 1) * 2 + ab) * 2 + h) * 16384;
        #pragma unroll
        for (int j = 0; j < 2; ++j) {
            const int row = (j * 8 + w) * 8 + r8;
            const signed char* src =
                g + (size_t)(grow0 + row) * K + kt * BKB + ((sl ^ r8) << 4);
            __builtin_amdgcn_global_load_lds(
                (const __attribute__((address_space(1))) void*)src,
                (__attribute__((address_space(3))) void*)(lb + ((j * 8 + w) * 64 + lane) * 16),
                16, 0, 0);
        }
    };

    auto LDA = [&](int buf, int mh, i32x4 A[4][2]) {
        const signed char* base = lds + ((buf * 2 + 0) * 2 + wr) * 16384;
        #pragma unroll
        for (int mf = 0; mf < 4; ++mf) {
            const int row = mh * 64 + mf * 16 + lrow;
            #pragma unroll
            for (int kk = 0; kk < 2; ++kk) {
                const int slot = (kk * 4 + ks) ^ (lrow & 7);
                A[mf][kk] = *reinterpret_cast<const i32x4*>(base + row * 128 + slot * 16);
            }
        }
    };
    auto LDB = [&](int buf, int nh, i32x4 B[2][2]) {
        const signed char* base = lds + ((buf * 2 + 1) * 2 + (wc >> 1)) * 16384;
        #pragma unroll
        for (int nf = 0; nf < 2; ++nf) {
            const int row = (wc & 1) * 64 + nh * 32 + nf * 16 + lrow;
            #pragma unroll
            for (int kk = 0; kk < 2; ++kk) {
                const int slot = (kk * 4 + ks) ^ (lrow & 7);
                B[nf][kk] = *reinterpret_cast<const i32x4*>(base + row * 128 + slot * 16);
            }
        }
    };
    auto MM = [&](int mh, int nh, i32x4 A[4][2], i32x4 B[2][2]) {
        __builtin_amdgcn_s_setprio(1);
        #pragma unroll
        for (int mf = 0; mf < 4; ++mf)
            #pragma unroll
            for (int nf = 0; nf < 2; ++nf)
                #pragma unroll
                for (int kk = 0; kk < 2; ++kk)
                    acc[mh * 4 + mf][nh * 2 + nf] = __builtin_amdgcn_mfma_i32_16x16x64_i8(
                        A[mf][kk], B[nf][kk], acc[mh * 4 + mf][nh * 2 + nf], 0, 0, 0);
        __builtin_amdgcn_s_setprio(0);
    };

    // ---- prologue ----
    STAGE(0, 1, 0); STAGE(0, 1, 1); STAGE(0, 0, 0); STAGE(0, 0, 1);
    STAGE(1, 1, 0); STAGE(1, 1, 1);
    asm volatile("s_waitcnt vmcnt(4)" ::: "memory");
    BAR();

    #pragma unroll
    for (int it = 0; it < NTILES / 2; ++it) {
        const int T = 2 * it;
        // P1
        LDA(0, 0, Ar); LDB(0, 0, Br[0]);
        STAGE(T + 1, 0, 0);
        BAR(); LGKM0();
        MM(0, 0, Ar, Br[0]);
        BAR();
        // P2
        LDB(0, 1, Br[1]);
        STAGE(T + 1, 0, 1);
        BAR(); LGKM0();
        MM(0, 1, Ar, Br[1]);
        BAR();
        // P3
        LDA(0, 1, Ar);
        if (T + 2 < NTILES) STAGE(T + 2, 1, 0);
        BAR(); LGKM0();
        MM(1, 0, Ar, Br[0]);
        BAR();
        // P4
        if (T + 2 < NTILES) STAGE(T + 2, 1, 1);
        MM(1, 1, Ar, Br[1]);
        if (T + 2 < NTILES) { asm volatile("s_waitcnt vmcnt(4)" ::: "memory"); }
        else                { asm volatile("s_waitcnt vmcnt(0)" ::: "memory"); }
        BAR();
        // P5
        LDA(1, 0, Ar); LDB(1, 0, Br[0]);
        if (T + 2 < NTILES) STAGE(T + 2, 0, 0);
        BAR(); LGKM0();
        MM(0, 0, Ar, Br[0]);
        BAR();
        // P6
        LDB(1, 1, Br[1]);
        if (T + 2 < NTILES) STAGE(T + 2, 0, 1);
        BAR(); LGKM0();
        MM(0, 1, Ar, Br[1]);
        BAR();
        // P7
        LDA(1, 1, Ar);
        if (T + 3 < NTILES) STAGE(T + 3, 1, 0);
        BAR(); LGKM0();
        MM(1, 0, Ar, Br[0]);
        BAR();
        // P8
        if (T + 3 < NTILES) STAGE(T + 3, 1, 1);
        MM(1, 1, Ar, Br[1]);
        if (T + 3 < NTILES) { asm volatile("s_waitcnt vmcnt(4)" ::: "memory"); }
        BAR();
    }

    // ---- epilogue: dequant + bias (normal stores — L2 write-back drains) ----
    #pragma unroll
    for (int mf = 0; mf < 8; ++mf) {
        #pragma unroll
        for (int r = 0; r < 4; ++r) {
            const int gm = m0 + wr * 128 + mf * 16 + ks * 4 + r;
            float* orow = out + (size_t)gm * N;
            #pragma unroll
            for (int nf = 0; nf < 4; ++nf)
                orow[gnc[nf]] = (float)acc[mf][nf][r] * wsv[nf] + bv[nf];
        }
    }
}

// ---------------------------------------------------------------------------
extern "C" void kernel_launch(void* const* d_in, const int* in_sizes, int n_in,
                              void* d_out, int out_size, void* d_ws, size_t ws_size,
                              hipStream_t stream)
{
    const float* x         = (const float*)d_in[0];
    const float* weight    = (const float*)d_in[1];
    const float* bias      = (const float*)d_in[2];
    const float* act_scale = (const float*)d_in[3];
    float* out             = (float*)d_out;

    const int K = 1024;
    const int N = 1024;
    const int M = in_sizes[0] / K;   // 32768

    // workspace: qw (N*K int8) | wscale (N f32, padded) | xq (M*K int8)
    char* wsb = (char*)d_ws;
    signed char* qw  = (signed char*)wsb;
    float*       wsc = (float*)(wsb + (size_t)N * K);
    signed char* xq  = (signed char*)(wsb + (size_t)N * K + 4096);

    quant_w_kernel<<<N, 256, 0, stream>>>(weight, act_scale, qw, wsc);
    quant_x_kernel<<<(int)(((size_t)M * K) / 1024), 256, 0, stream>>>(x, act_scale, xq);

    const int grid = (M / BM) * (N / BN);   // 512, divisible by 8
    gemm_i8_kernel<<<grid, 512, 0, stream>>>(xq, qw, wsc, bias, out, M);
}